// Round 13
// baseline (293.056 us; speedup 1.0000x reference)
//
#include <hip/hip_runtime.h>
#include <math.h>

#define HH   128
#define WW   128
#define HWP  16384      // H*W
#define CIN  64
#define COUT 128

typedef float  f32x4  __attribute__((ext_vector_type(4)));
typedef short  short8 __attribute__((ext_vector_type(8)));

// ws layout (bytes): wbf [128][576] bf16 @0 (147456); owbf [32][576] bf16 @147456
// (73728); xt NHWC bf16 [4*16384][64] @221184 (8388608). NEED = 8609792.
#define WBF_B   ((size_t)0)
#define OWBF_B  ((size_t)147456)
#define XT_B    ((size_t)221184)
#define WS_NEED ((size_t)8609792)

__device__ inline unsigned short f2bf(float f) {
    unsigned u = __builtin_bit_cast(unsigned, f);
    return (unsigned short)((u + 0x7FFFu + ((u >> 16) & 1u)) >> 16);   // RNE
}

// ---------------- prep: bf16 weight transposes ----------------
__global__ __launch_bounds__(256) void k_prep_w(const float* __restrict__ wgt,
                                                const float* __restrict__ ow,
                                                unsigned short* __restrict__ wbf,
                                                unsigned short* __restrict__ owbf) {
    int tid = blockIdx.x * 256 + threadIdx.x;   // 288*256 = 73728 exactly
    {
        int oc = tid / 576;
        int r  = tid - oc * 576;
        int kk = r >> 6;
        int c  = r & 63;
        wbf[tid] = f2bf(wgt[((size_t)oc * CIN + c) * 9 + kk]);
    }
    if (tid < 32 * 576) {
        int oc  = tid / 576;
        int r   = tid - oc * 576;
        int tap = r >> 6;
        int c   = r & 63;
        owbf[tid] = (oc < 27) ? f2bf(ow[((size_t)oc * CIN + c) * 9 + tap]) : 0;
    }
}

// ---------------- prep: x NCHW fp32 -> NHWC bf16 ----------------
__global__ __launch_bounds__(256) void k_xt(const float* __restrict__ x,
                                            unsigned short* __restrict__ xt) {
    int t = threadIdx.x;
    int cgrp = t & 7, px = t >> 3;            // px 0..31
    int pix = blockIdx.x * 32 + px;           // grid 2048
    int b = pix >> 14, hw = pix & 16383;
    const float* xp = x + (size_t)b * CIN * HWP + (size_t)(cgrp * 8) * HWP + hw;
    unsigned pk[4];
#pragma unroll
    for (int d = 0; d < 4; ++d) {
        float lo = xp[(size_t)(2 * d) * HWP];
        float hi = xp[(size_t)(2 * d + 1) * HWP];
        pk[d] = (unsigned)f2bf(lo) | ((unsigned)f2bf(hi) << 16);
    }
    *(uint4*)(xt + (size_t)pix * 64 + cgrp * 8) = *(uint4*)pk;
}

// weighted bf16x8 combine of 4 corner slices (uint4 = 8 packed bf16 each)
__device__ inline short8 combine4(uint4 u0, uint4 u1, uint4 u2, uint4 u3,
                                  float w0, float w1, float w2, float w3) {
    unsigned pk[4];
#pragma unroll
    for (int d = 0; d < 4; ++d) {
        unsigned a = (&u0.x)[d], b = (&u1.x)[d], c = (&u2.x)[d], e = (&u3.x)[d];
        float lo = w0 * __builtin_bit_cast(float, a << 16)
                 + w1 * __builtin_bit_cast(float, b << 16)
                 + w2 * __builtin_bit_cast(float, c << 16)
                 + w3 * __builtin_bit_cast(float, e << 16);
        float hi = w0 * __builtin_bit_cast(float, a & 0xFFFF0000u)
                 + w1 * __builtin_bit_cast(float, b & 0xFFFF0000u)
                 + w2 * __builtin_bit_cast(float, c & 0xFFFF0000u)
                 + w3 * __builtin_bit_cast(float, e & 0xFFFF0000u);
        pk[d] = (unsigned)f2bf(lo) | ((unsigned)f2bf(hi) << 16);
    }
    uint4 r = {pk[0], pk[1], pk[2], pk[3]};
    return __builtin_bit_cast(short8, r);
}

// ================= v4: wave-autonomous 16px x 32oc (zero barriers) =========
// wave tile: gtile = blk*4+wid; oc-chunk = gtile&3 (32 oc), px-tile = gtile>>2.
// The 4 waves of a block are 4 oc-chunks of the SAME px-tile -> shared corner
// records hit L1. Per kk per wave: 8 corner + 4 A loads + 4 MFMA (v2's A rate,
// v3's barrier-freedom). Bilinear/stage-A duplicated 4x = VALU (22% busy -> ok).
__global__ __launch_bounds__(256) void k_fused_v4(const unsigned short* __restrict__ xt,
                                                  const unsigned short* __restrict__ wbf,
                                                  const unsigned short* __restrict__ owbf,
                                                  const float* __restrict__ ob,
                                                  const float* __restrict__ bias,
                                                  float* __restrict__ out) {
    __shared__ __align__(16) float smeta[4 * 432];   // per-wave [3][9][16]

    int t   = threadIdx.x;
    int wid = t >> 6;
    int l   = t & 63;
    int n   = l & 15;                    // pixel in tile / A-row / B-col
    int kq  = l >> 4;                    // k-quarter

    int gtile = blockIdx.x * 4 + wid;    // 0..16383
    int ocb   = (gtile & 3) * 32;        // wave's 32-oc chunk
    int pt    = gtile >> 2;              // px-tile 0..4095
    int b   = pt >> 10;
    int rem = pt & 1023;
    int h   = rem >> 3;
    int w0  = (rem & 7) << 4;

    const unsigned short* xbt = xt + (size_t)b * HWP * 64;
    float* metaW = smeta + wid * 432;

    // ===== stage A: offset conv (B direct from xt, A from owbf) =====
    f32x4 sacc0 = {0.f,0.f,0.f,0.f};     // oc 0..15
    f32x4 sacc1 = {0.f,0.f,0.f,0.f};     // oc 16..31
    const unsigned short* sa0 = owbf + (size_t)n * 576 + kq * 8;
    const unsigned short* sa1 = sa0 + 16 * 576;

#pragma unroll
    for (int tap = 0; tap < 9; ++tap) {
        int ky = tap / 3, kx = tap % 3;
        int yy = h - 1 + ky;
        int xx = w0 + n - 1 + kx;
        bool vld = (yy >= 0) && (yy < HH) && (xx >= 0) && (xx < WW);
        int yc = min(max(yy, 0), HH - 1), xc = min(max(xx, 0), WW - 1);
        const unsigned short* rec = xbt + (size_t)(yc * WW + xc) * 64 + kq * 8;
        uint4 v0 = *(const uint4*)rec;
        uint4 v1 = *(const uint4*)(rec + 32);
        if (!vld) { v0 = uint4{0,0,0,0}; v1 = uint4{0,0,0,0}; }
        short8 a00 = *(const short8*)(sa0 + tap * 64);
        short8 a01 = *(const short8*)(sa0 + tap * 64 + 32);
        short8 a10 = *(const short8*)(sa1 + tap * 64);
        short8 a11 = *(const short8*)(sa1 + tap * 64 + 32);
        sacc0 = __builtin_amdgcn_mfma_f32_16x16x32_bf16(a00, __builtin_bit_cast(short8, v0), sacc0, 0, 0, 0);
        sacc0 = __builtin_amdgcn_mfma_f32_16x16x32_bf16(a01, __builtin_bit_cast(short8, v1), sacc0, 0, 0, 0);
        sacc1 = __builtin_amdgcn_mfma_f32_16x16x32_bf16(a10, __builtin_bit_cast(short8, v0), sacc1, 0, 0, 0);
        sacc1 = __builtin_amdgcn_mfma_f32_16x16x32_bf16(a11, __builtin_bit_cast(short8, v1), sacc1, 0, 0, 0);
    }
    // meta -> per-wave LDS (C map: col=n, row=kq*4+r). No barrier: same wave.
#pragma unroll
    for (int r = 0; r < 4; ++r) {
        int oc0 = kq * 4 + r;            // 0..15: always offset plane
        metaW[(oc0 & 1) * 144 + (oc0 >> 1) * 16 + n] = sacc0[r] + ob[oc0];
        int oc1 = 16 + kq * 4 + r;       // 16..31
        if (oc1 < 18) {
            metaW[(oc1 & 1) * 144 + (oc1 >> 1) * 16 + n] = sacc1[r] + ob[oc1];
        } else if (oc1 < 27) {
            float v = sacc1[r] + ob[oc1];
            metaW[2 * 144 + (oc1 - 18) * 16 + n] = 1.f / (1.f + expf(-v));
        }
    }
    asm volatile("s_waitcnt lgkmcnt(0)" ::: "memory");   // meta visible to own wave

    // ===== main: 9 kk, in-register bilinear B-frags, 4 MFMA per kk =====
    f32x4 acc0 = {0.f,0.f,0.f,0.f};      // oc ocb+0..15
    f32x4 acc1 = {0.f,0.f,0.f,0.f};      // oc ocb+16..31
    const unsigned short* awb = wbf + (size_t)(ocb + n) * 576 + kq * 8;

#pragma unroll
    for (int kk = 0; kk < 9; ++kk) {
        float offy = metaW[kk * 16 + n];
        float offx = metaW[144 + kk * 16 + n];
        float msk  = metaW[288 + kk * 16 + n];
        int ky = kk / 3, kx = kk % 3;
        float py = (float)(h - 1 + ky) + offy;
        float px = (float)(w0 + n - 1 + kx) + offx;
        float y0f = floorf(py), x0f = floorf(px);
        float ly = py - y0f, lx = px - x0f;
        int y0 = (int)y0f, x0i = (int)x0f;
        int y1 = y0 + 1, x1 = x0i + 1;
        bool vy0 = (y0 >= 0) && (y0 < HH);
        bool vy1 = (y1 >= 0) && (y1 < HH);
        bool vx0 = (x0i >= 0) && (x0i < WW);
        bool vx1 = (x1 >= 0) && (x1 < WW);
        int yc0 = min(max(y0, 0), HH - 1), yc1 = min(max(y1, 0), HH - 1);
        int xc0 = min(max(x0i, 0), WW - 1), xc1 = min(max(x1, 0), WW - 1);
        float w00 = (1.f - ly) * (1.f - lx) * ((vy0 && vx0) ? msk : 0.f);
        float w01 = (1.f - ly) * lx         * ((vy0 && vx1) ? msk : 0.f);
        float w10 = ly * (1.f - lx)         * ((vy1 && vx0) ? msk : 0.f);
        float w11 = ly * lx                 * ((vy1 && vx1) ? msk : 0.f);
        const unsigned short* r00 = xbt + (size_t)(yc0 * WW + xc0) * 64 + kq * 8;
        const unsigned short* r01 = xbt + (size_t)(yc0 * WW + xc1) * 64 + kq * 8;
        const unsigned short* r10 = xbt + (size_t)(yc1 * WW + xc0) * 64 + kq * 8;
        const unsigned short* r11 = xbt + (size_t)(yc1 * WW + xc1) * 64 + kq * 8;
        uint4 c00a = *(const uint4*)r00, c00b = *(const uint4*)(r00 + 32);
        uint4 c01a = *(const uint4*)r01, c01b = *(const uint4*)(r01 + 32);
        uint4 c10a = *(const uint4*)r10, c10b = *(const uint4*)(r10 + 32);
        uint4 c11a = *(const uint4*)r11, c11b = *(const uint4*)(r11 + 32);
        short8 b0 = combine4(c00a, c01a, c10a, c11a, w00, w01, w10, w11);
        short8 b1 = combine4(c00b, c01b, c10b, c11b, w00, w01, w10, w11);
        const unsigned short* ar0 = awb + kk * 64;
        const unsigned short* ar1 = ar0 + (size_t)16 * 576;
        short8 a00 = *(const short8*)ar0;
        short8 a01 = *(const short8*)(ar0 + 32);
        short8 a10 = *(const short8*)ar1;
        short8 a11 = *(const short8*)(ar1 + 32);
        acc0 = __builtin_amdgcn_mfma_f32_16x16x32_bf16(a00, b0, acc0, 0, 0, 0);
        acc0 = __builtin_amdgcn_mfma_f32_16x16x32_bf16(a01, b1, acc0, 0, 0, 0);
        acc1 = __builtin_amdgcn_mfma_f32_16x16x32_bf16(a10, b0, acc1, 0, 0, 0);
        acc1 = __builtin_amdgcn_mfma_f32_16x16x32_bf16(a11, b1, acc1, 0, 0, 0);
    }

    // ===== epilogue: bias + stores (C map: col=n -> px, row=kq*4+r -> oc) =====
    size_t outb = (size_t)b * COUT * HWP + (size_t)h * WW + w0 + n;
#pragma unroll
    for (int r = 0; r < 4; ++r) {
        int oc0 = ocb + kq * 4 + r;
        out[outb + (size_t)oc0 * HWP] = acc0[r] + bias[oc0];
        int oc1 = oc0 + 16;
        out[outb + (size_t)oc1 * HWP] = acc1[r] + bias[oc1];
    }
}

// ================= v1 fallback (R8 kernel, validated; used if ws too small) ====
__global__ __launch_bounds__(256) void k_fused_v1(const float* __restrict__ x,
                                                  const unsigned short* __restrict__ wbf,
                                                  const unsigned short* __restrict__ owbf,
                                                  const float* __restrict__ ob,
                                                  const float* __restrict__ bias,
                                                  float* __restrict__ out) {
    __shared__ __align__(16) char smem[16768];
    char*  ctx    = smem;
    char*  mbase  = smem;
    float* meta_s = (float*)(smem + 13312);

    int blk = blockIdx.x;
    int b   = blk >> 9;
    int rem = blk & 511;
    int h   = rem >> 2;
    int w0  = (rem & 3) << 5;
    int t   = threadIdx.x;

    int p1 = t & 31;
    int cg = t >> 5;
    int l  = t & 63;
    int wid = t >> 6;
    int lm = l & 15, lk = l >> 4;

    const float* xb = x + (size_t)b * CIN * HWP;

#pragma unroll
    for (int c = 0; c < 4; ++c) {
        int j = c * 256 + t;
        if (j < 816) {
            int g   = j / 34;
            int px  = j - g * 34;
            int row = g >> 3;
            int cgj = g & 7;
            int yy = h - 1 + row;
            int xx = w0 - 1 + px;
            bool vld = (yy >= 0) && (yy < HH) && (xx >= 0) && (xx < WW);
            int  sidx = vld ? (yy * WW + xx) : 0;
            float s[8];
#pragma unroll
            for (int i = 0; i < 8; ++i)
                s[i] = vld ? xb[(size_t)(cgj * 8 + i) * HWP + sidx] : 0.f;
            uint4 pk;
            pk.x = (unsigned)f2bf(s[0]) | ((unsigned)f2bf(s[1]) << 16);
            pk.y = (unsigned)f2bf(s[2]) | ((unsigned)f2bf(s[3]) << 16);
            pk.z = (unsigned)f2bf(s[4]) | ((unsigned)f2bf(s[5]) << 16);
            pk.w = (unsigned)f2bf(s[6]) | ((unsigned)f2bf(s[7]) << 16);
            *(uint4*)(ctx + (row * 34 + px) * 128 + ((cgj ^ (px & 7)) << 4)) = pk;
        }
    }
    __syncthreads();

    int ocf = wid >> 1, pxf = wid & 1;
    int spx = pxf * 16 + lm;
    f32x4 sacc = {0.f, 0.f, 0.f, 0.f};
    const unsigned short* sab = owbf + (size_t)(ocf * 16 + lm) * 576 + lk * 8;

#pragma unroll
    for (int tap = 0; tap < 9; ++tap) {
        int ky = tap / 3, kx = tap % 3;
        int cpx = kx + spx;
        int crb = (ky * 34 + cpx) * 128;
        int csw = cpx & 7;
#pragma unroll
        for (int ch = 0; ch < 2; ++ch) {
            short8 a  = *(const short8*)(sab + tap * 64 + ch * 32);
            int kb = ch * 4 + lk;
            short8 bf = *(const short8*)(ctx + crb + (((unsigned)(kb ^ csw)) << 4));
            sacc = __builtin_amdgcn_mfma_f32_16x16x32_bf16(a, bf, sacc, 0, 0, 0);
        }
    }
#pragma unroll
    for (int r = 0; r < 4; ++r) {
        int oc = ocf * 16 + lk * 4 + r;
        if (oc < 27) {
            float v = sacc[r] + ob[oc];
            if (oc < 18) {
                meta_s[(oc & 1) * 288 + (oc >> 1) * 32 + spx] = v;
            } else {
                meta_s[2 * 288 + (oc - 18) * 32 + spx] = 1.f / (1.f + expf(-v));
            }
        }
    }
    __syncthreads();

    f32x4 acc00 = {0.f,0.f,0.f,0.f};
    f32x4 acc01 = {0.f,0.f,0.f,0.f};
    f32x4 acc10 = {0.f,0.f,0.f,0.f};
    f32x4 acc11 = {0.f,0.f,0.f,0.f};

    const unsigned short* arow0 = wbf + (size_t)(wid * 32 + lm) * 576 + lk * 8;
    const unsigned short* arow1 = arow0 + 16 * 576;

    int pA = lm, pB = lm + 16;
    int rbA = pA * 128, rbB = pB * 128;
    int swA = pA & 7,   swB = pB & 7;

    float  cw00, cw01, cw10, cw11;
    float  cc00[8], cc01[8], cc10[8], cc11[8];
    short8 na0[2], na1[2];

#define PREF_CORNERS(KK) do {                                                  \
      int ky = (KK) / 3, kx = (KK) % 3;                                        \
      float offy = meta_s[(KK) * 32 + p1];                                     \
      float offx = meta_s[288 + (KK) * 32 + p1];                               \
      float msk  = meta_s[576 + (KK) * 32 + p1];                               \
      float py = (float)(h - 1 + ky) + offy;                                   \
      float px = (float)(w0 + p1 - 1 + kx) + offx;                             \
      float y0f = floorf(py), x0f = floorf(px);                                \
      float ly = py - y0f, lx = px - x0f;                                      \
      int y0 = (int)y0f, x0i = (int)x0f;                                       \
      int y1 = y0 + 1, x1 = x0i + 1;                                           \
      bool vy0 = (y0 >= 0) && (y0 < HH);                                       \
      bool vy1 = (y1 >= 0) && (y1 < HH);                                       \
      bool vx0 = (x0i >= 0) && (x0i < WW);                                     \
      bool vx1 = (x1 >= 0) && (x1 < WW);                                       \
      int yc0 = min(max(y0, 0), HH - 1), yc1 = min(max(y1, 0), HH - 1);        \
      int xc0 = min(max(x0i, 0), WW - 1), xc1 = min(max(x1, 0), WW - 1);       \
      cw00 = (1.f - ly) * (1.f - lx) * ((vy0 && vx0) ? msk : 0.f);             \
      cw01 = (1.f - ly) * lx         * ((vy0 && vx1) ? msk : 0.f);             \
      cw10 = ly * (1.f - lx)         * ((vy1 && vx0) ? msk : 0.f);             \
      cw11 = ly * lx                 * ((vy1 && vx1) ? msk : 0.f);             \
      int idx00 = yc0 * WW + xc0, idx01 = yc0 * WW + xc1;                      \
      int idx10 = yc1 * WW + xc0, idx11 = yc1 * WW + xc1;                      \
      const float* basec = xb + (size_t)(cg * 8) * HWP;                        \
      _Pragma("unroll")                                                        \
      for (int i = 0; i < 8; ++i) {                                            \
        const float* bc = basec + (size_t)i * HWP;                             \
        cc00[i] = bc[idx00]; cc01[i] = bc[idx01];                              \
        cc10[i] = bc[idx10]; cc11[i] = bc[idx11];                              \
      }                                                                        \
    } while (0)

#define PREF_AFRAG(KK) do {                                                    \
      na0[0] = *(const short8*)(arow0 + (KK) * 64);                            \
      na0[1] = *(const short8*)(arow0 + (KK) * 64 + 32);                       \
      na1[0] = *(const short8*)(arow1 + (KK) * 64);                            \
      na1[1] = *(const short8*)(arow1 + (KK) * 64 + 32);                       \
    } while (0)

    PREF_CORNERS(0);
    PREF_AFRAG(0);

#pragma unroll
    for (int kk = 0; kk < 9; ++kk) {
        {
            char* wdst = mbase + (kk & 1) * 4096;
            float s[8];
#pragma unroll
            for (int i = 0; i < 8; ++i)
                s[i] = cw00 * cc00[i] + cw01 * cc01[i]
                     + cw10 * cc10[i] + cw11 * cc11[i];
            uint4 pk;
            pk.x = (unsigned)f2bf(s[0]) | ((unsigned)f2bf(s[1]) << 16);
            pk.y = (unsigned)f2bf(s[2]) | ((unsigned)f2bf(s[3]) << 16);
            pk.z = (unsigned)f2bf(s[4]) | ((unsigned)f2bf(s[5]) << 16);
            pk.w = (unsigned)f2bf(s[6]) | ((unsigned)f2bf(s[7]) << 16);
            *(uint4*)(wdst + p1 * 128 + (((unsigned)(cg ^ (p1 & 7))) << 4)) = pk;
        }
        if (kk < 8) PREF_CORNERS(kk + 1);
        asm volatile("s_waitcnt lgkmcnt(0)" ::: "memory");
        __builtin_amdgcn_s_barrier();
        __builtin_amdgcn_sched_barrier(0);
        const char* rb = mbase + (kk & 1) * 4096;
#pragma unroll
        for (int sstep = 0; sstep < 2; ++sstep) {
            short8 a0 = na0[sstep];
            short8 a1 = na1[sstep];
            int kb = sstep * 4 + lk;
            short8 b0 = *(const short8*)(rb + rbA + ((kb ^ swA) << 4));
            short8 b1 = *(const short8*)(rb + rbB + ((kb ^ swB) << 4));
            acc00 = __builtin_amdgcn_mfma_f32_16x16x32_bf16(a0, b0, acc00, 0, 0, 0);
            acc01 = __builtin_amdgcn_mfma_f32_16x16x32_bf16(a0, b1, acc01, 0, 0, 0);
            acc10 = __builtin_amdgcn_mfma_f32_16x16x32_bf16(a1, b0, acc10, 0, 0, 0);
            acc11 = __builtin_amdgcn_mfma_f32_16x16x32_bf16(a1, b1, acc11, 0, 0, 0);
        }
        if (kk < 8) PREF_AFRAG(kk + 1);
    }
#undef PREF_CORNERS
#undef PREF_AFRAG

    size_t outb = (size_t)b * COUT * HWP + (size_t)h * WW + w0;
#pragma unroll
    for (int of = 0; of < 2; ++of) {
        f32x4 aP = of ? acc10 : acc00;
        f32x4 aQ = of ? acc11 : acc01;
        int ocb = wid * 32 + of * 16 + lk * 4;
#pragma unroll
        for (int r = 0; r < 4; ++r) {
            int oc = ocb + r;
            float bi = bias[oc];
            out[outb + (size_t)oc * HWP + pA] = aP[r] + bi;
            out[outb + (size_t)oc * HWP + pB] = aQ[r] + bi;
        }
    }
}

extern "C" void kernel_launch(void* const* d_in, const int* in_sizes, int n_in,
                              void* d_out, int out_size, void* d_ws, size_t ws_size,
                              hipStream_t stream) {
    const float* x    = (const float*)d_in[0];
    const float* ow   = (const float*)d_in[1];
    const float* ob   = (const float*)d_in[2];
    const float* wgt  = (const float*)d_in[3];
    const float* bias = (const float*)d_in[4];
    float* out = (float*)d_out;
    char* ws = (char*)d_ws;

    unsigned short* wbf  = (unsigned short*)(ws + WBF_B);
    unsigned short* owbf = (unsigned short*)(ws + OWBF_B);
    unsigned short* xt   = (unsigned short*)(ws + XT_B);

    hipLaunchKernelGGL(k_prep_w, dim3(288), dim3(256), 0, stream, wgt, ow, wbf, owbf);
    if (ws_size >= WS_NEED) {
        hipLaunchKernelGGL(k_xt, dim3(2048), dim3(256), 0, stream, x, xt);
        hipLaunchKernelGGL(k_fused_v4, dim3(4096), dim3(256), 0, stream,
                           xt, wbf, owbf, ob, bias, out);
    } else {
        hipLaunchKernelGGL(k_fused_v1, dim3(2048), dim3(256), 0, stream,
                           x, wbf, owbf, ob, bias, out);
    }
}

// Round 14
// 96.685 us; speedup vs baseline: 3.0310x; 3.0310x over previous
//
#include <hip/hip_runtime.h>
#include <math.h>

#define HH   128
#define WW   128
#define HWP  16384      // H*W
#define CIN  64
#define COUT 128

typedef float  f32x4  __attribute__((ext_vector_type(4)));
typedef short  short8 __attribute__((ext_vector_type(8)));

// ws layout (bytes): wbf [128][576] bf16 @0 (147456); owbf [32][576] bf16 @147456
// (73728); xt NHWC bf16 [4*16384][64] @221184 (8388608). NEED = 8609792.
#define WBF_B   ((size_t)0)
#define OWBF_B  ((size_t)147456)
#define XT_B    ((size_t)221184)
#define WS_NEED ((size_t)8609792)

__device__ inline unsigned short f2bf(float f) {
    unsigned u = __builtin_bit_cast(unsigned, f);
    return (unsigned short)((u + 0x7FFFu + ((u >> 16) & 1u)) >> 16);   // RNE
}

// ---------------- prep: bf16 weight transposes ----------------
__global__ __launch_bounds__(256) void k_prep_w(const float* __restrict__ wgt,
                                                const float* __restrict__ ow,
                                                unsigned short* __restrict__ wbf,
                                                unsigned short* __restrict__ owbf) {
    int tid = blockIdx.x * 256 + threadIdx.x;   // 288*256 = 73728 exactly
    {
        int oc = tid / 576;
        int r  = tid - oc * 576;
        int kk = r >> 6;
        int c  = r & 63;
        wbf[tid] = f2bf(wgt[((size_t)oc * CIN + c) * 9 + kk]);
    }
    if (tid < 32 * 576) {
        int oc  = tid / 576;
        int r   = tid - oc * 576;
        int tap = r >> 6;
        int c   = r & 63;
        owbf[tid] = (oc < 27) ? f2bf(ow[((size_t)oc * CIN + c) * 9 + tap]) : 0;
    }
}

// ---------------- prep: x NCHW fp32 -> NHWC bf16 ----------------
__global__ __launch_bounds__(256) void k_xt(const float* __restrict__ x,
                                            unsigned short* __restrict__ xt) {
    int t = threadIdx.x;
    int cgrp = t & 7, px = t >> 3;            // px 0..31
    int pix = blockIdx.x * 32 + px;           // grid 2048
    int b = pix >> 14, hw = pix & 16383;
    const float* xp = x + (size_t)b * CIN * HWP + (size_t)(cgrp * 8) * HWP + hw;
    unsigned pk[4];
#pragma unroll
    for (int d = 0; d < 4; ++d) {
        float lo = xp[(size_t)(2 * d) * HWP];
        float hi = xp[(size_t)(2 * d + 1) * HWP];
        pk[d] = (unsigned)f2bf(lo) | ((unsigned)f2bf(hi) << 16);
    }
    *(uint4*)(xt + (size_t)pix * 64 + cgrp * 8) = *(uint4*)pk;
}

// ================= v2: NHWC-bf16 fused kernel (R11 structure) =================
// block = 32 pixels of one row x all 128 oc; 256 threads; LDS 11.6 KB
// staging lane map: cg = t&7, px = t>>3 (R11's +18% lever).
// R13 trim: A-frag prefetch (na0/na1, 16 VGPRs) removed -- A loaded inline at
// MFMA time (wbf is L2-resident, shared by all blocks). Target: VGPR<=64 so
// waves/CU doubles (m69: occupancy halves above 64 VGPRs). R10 lesson: do NOT
// force via __launch_bounds__ min-waves (spills); let the allocator land there.
__global__ __launch_bounds__(256) void k_fused_v2(const unsigned short* __restrict__ xt,
                                                  const unsigned short* __restrict__ wbf,
                                                  const unsigned short* __restrict__ owbf,
                                                  const float* __restrict__ ob,
                                                  const float* __restrict__ bias,
                                                  float* __restrict__ out) {
    __shared__ __align__(16) char smem[11648];
    char*  mbase  = smem;                    // 2 x 4KB bf16 [32p][64k] swizzled dbuf
    float* meta_s = (float*)(smem + 8192);   // [comp][kk][p] 3456B

    int blk = blockIdx.x;                 // 2048
    int b   = blk >> 9;
    int rem = blk & 511;
    int h   = rem >> 2;
    int w0  = (rem & 3) << 5;
    int t   = threadIdx.x;

    int p1 = t >> 3;                      // pixel in tile (staging role)
    int cg = t & 7;                       // 8-channel group (staging role)
    int l  = t & 63;
    int wid = t >> 6;                     // wave id
    int lm = l & 15, lk = l >> 4;

    const unsigned short* xbt = xt + (size_t)b * HWP * 64;

    // ===== stage A: offset conv, B-frags DIRECT from global xt (no LDS) =====
    int ocf = wid >> 1, pxf = wid & 1;    // wave quadrant: oc[ocf*16+), px[pxf*16+)
    int spx = pxf * 16 + lm;
    f32x4 sacc = {0.f, 0.f, 0.f, 0.f};
    const unsigned short* sab = owbf + (size_t)(ocf * 16 + lm) * 576 + lk * 8;

#pragma unroll
    for (int tap = 0; tap < 9; ++tap) {
        int ky = tap / 3, kx = tap % 3;
        int yy = h - 1 + ky;
        int xx = w0 - 1 + kx + spx;
        bool vld = (yy >= 0) && (yy < HH) && (xx >= 0) && (xx < WW);
        int yc = min(max(yy, 0), HH - 1), xc = min(max(xx, 0), WW - 1);
        const unsigned short* bp = xbt + (size_t)(yc * WW + xc) * 64 + lk * 8;
#pragma unroll
        for (int ch = 0; ch < 2; ++ch) {
            short8 a = *(const short8*)(sab + tap * 64 + ch * 32);
            uint4 v = *(const uint4*)(bp + ch * 32);
            v.x = vld ? v.x : 0u;  v.y = vld ? v.y : 0u;
            v.z = vld ? v.z : 0u;  v.w = vld ? v.w : 0u;
            sacc = __builtin_amdgcn_mfma_f32_16x16x32_bf16(a, __builtin_bit_cast(short8, v), sacc, 0, 0, 0);
        }
    }
    // postprocess own quadrant -> meta_s (C map: col=lane&15 -> px, row=lk*4+r -> oc)
#pragma unroll
    for (int r = 0; r < 4; ++r) {
        int oc = ocf * 16 + lk * 4 + r;
        if (oc < 27) {
            float v = sacc[r] + ob[oc];
            if (oc < 18) {
                meta_s[(oc & 1) * 288 + (oc >> 1) * 32 + spx] = v;
            } else {
                meta_s[2 * 288 + (oc - 18) * 32 + spx] = 1.f / (1.f + expf(-v));
            }
        }
    }
    __syncthreads();   // meta_s ready

    // ================= main: pipelined bilinear (bf16x8 corners) -> MFMA =======
    f32x4 acc00 = {0.f,0.f,0.f,0.f};
    f32x4 acc01 = {0.f,0.f,0.f,0.f};
    f32x4 acc10 = {0.f,0.f,0.f,0.f};
    f32x4 acc11 = {0.f,0.f,0.f,0.f};

    const unsigned short* arow0 = wbf + (size_t)(wid * 32 + lm) * 576 + lk * 8;
    const unsigned short* arow1 = arow0 + 16 * 576;

    int pA = lm, pB = lm + 16;
    int rbA = pA * 128, rbB = pB * 128;
    int swA = pA & 7,   swB = pB & 7;

    // pipeline registers: 2-slot corner buffers (fully unrolled -> static idx)
    uint4 cc00[2], cc01[2], cc10[2], cc11[2];
    float cw00[2], cw01[2], cw10[2], cw11[2];

    const unsigned short* xbc = xbt + cg * 8;   // this thread's channel slice

#define PREF_CORNERS(KK, BUF) do {                                             \
      int ky_ = (KK) / 3, kx_ = (KK) % 3;                                      \
      float offy = meta_s[(KK) * 32 + p1];                                     \
      float offx = meta_s[288 + (KK) * 32 + p1];                               \
      float msk  = meta_s[576 + (KK) * 32 + p1];                               \
      float py = (float)(h - 1 + ky_) + offy;                                  \
      float px = (float)(w0 + p1 - 1 + kx_) + offx;                            \
      float y0f = floorf(py), x0f = floorf(px);                                \
      float ly = py - y0f, lx = px - x0f;                                      \
      int y0 = (int)y0f, x0i = (int)x0f;                                       \
      int y1 = y0 + 1, x1 = x0i + 1;                                           \
      bool vy0 = (y0 >= 0) && (y0 < HH);                                       \
      bool vy1 = (y1 >= 0) && (y1 < HH);                                       \
      bool vx0 = (x0i >= 0) && (x0i < WW);                                     \
      bool vx1 = (x1 >= 0) && (x1 < WW);                                       \
      int yc0 = min(max(y0, 0), HH - 1), yc1 = min(max(y1, 0), HH - 1);        \
      int xc0 = min(max(x0i, 0), WW - 1), xc1 = min(max(x1, 0), WW - 1);       \
      cw00[BUF] = (1.f - ly) * (1.f - lx) * ((vy0 && vx0) ? msk : 0.f);        \
      cw01[BUF] = (1.f - ly) * lx         * ((vy0 && vx1) ? msk : 0.f);        \
      cw10[BUF] = ly * (1.f - lx)         * ((vy1 && vx0) ? msk : 0.f);        \
      cw11[BUF] = ly * lx                 * ((vy1 && vx1) ? msk : 0.f);        \
      cc00[BUF] = *(const uint4*)(xbc + (size_t)(yc0 * WW + xc0) * 64);        \
      cc01[BUF] = *(const uint4*)(xbc + (size_t)(yc0 * WW + xc1) * 64);        \
      cc10[BUF] = *(const uint4*)(xbc + (size_t)(yc1 * WW + xc0) * 64);        \
      cc11[BUF] = *(const uint4*)(xbc + (size_t)(yc1 * WW + xc1) * 64);        \
    } while (0)

    PREF_CORNERS(0, 0);

#pragma unroll
    for (int kk = 0; kk < 9; ++kk) {
        const int cur = kk & 1, nxt = (kk + 1) & 1;
        // ---- issue NEXT tile's corner loads first (deep overlap) ----
        if (kk < 8) PREF_CORNERS(kk + 1, nxt);

        // ---- combine (waits this tile's corners) + pack + swizzled LDS write --
        {
            char* wdst = mbase + cur * 4096;
            float w0c = cw00[cur], w1c = cw01[cur], w2c = cw10[cur], w3c = cw11[cur];
            unsigned pk[4];
#pragma unroll
            for (int d = 0; d < 4; ++d) {
                unsigned u0 = (&cc00[cur].x)[d], u1 = (&cc01[cur].x)[d];
                unsigned u2 = (&cc10[cur].x)[d], u3 = (&cc11[cur].x)[d];
                float lo = w0c * __builtin_bit_cast(float, u0 << 16)
                         + w1c * __builtin_bit_cast(float, u1 << 16)
                         + w2c * __builtin_bit_cast(float, u2 << 16)
                         + w3c * __builtin_bit_cast(float, u3 << 16);
                float hi = w0c * __builtin_bit_cast(float, u0 & 0xFFFF0000u)
                         + w1c * __builtin_bit_cast(float, u1 & 0xFFFF0000u)
                         + w2c * __builtin_bit_cast(float, u2 & 0xFFFF0000u)
                         + w3c * __builtin_bit_cast(float, u3 & 0xFFFF0000u);
                pk[d] = (unsigned)f2bf(lo) | ((unsigned)f2bf(hi) << 16);
            }
            *(uint4*)(wdst + p1 * 128 + (((unsigned)(cg ^ (p1 & 7))) << 4)) = *(uint4*)pk;
        }

        // ---- raw barrier: order LDS, leave global prefetches in flight ----
        asm volatile("s_waitcnt lgkmcnt(0)" ::: "memory");
        __builtin_amdgcn_s_barrier();
        __builtin_amdgcn_sched_barrier(0);

        // ---- MFMA (tile kk); A-frags loaded inline (L2-resident wbf) ----
        const char* rb = mbase + cur * 4096;
#pragma unroll
        for (int sstep = 0; sstep < 2; ++sstep) {
            short8 a0 = *(const short8*)(arow0 + kk * 64 + sstep * 32);
            short8 a1 = *(const short8*)(arow1 + kk * 64 + sstep * 32);
            int kb = sstep * 4 + lk;
            short8 b0 = *(const short8*)(rb + rbA + ((kb ^ swA) << 4));
            short8 b1 = *(const short8*)(rb + rbB + ((kb ^ swB) << 4));
            acc00 = __builtin_amdgcn_mfma_f32_16x16x32_bf16(a0, b0, acc00, 0, 0, 0);
            acc01 = __builtin_amdgcn_mfma_f32_16x16x32_bf16(a0, b1, acc01, 0, 0, 0);
            acc10 = __builtin_amdgcn_mfma_f32_16x16x32_bf16(a1, b0, acc10, 0, 0, 0);
            acc11 = __builtin_amdgcn_mfma_f32_16x16x32_bf16(a1, b1, acc11, 0, 0, 0);
        }
    }
#undef PREF_CORNERS

    // ---- epilogue: bias + stores ----
    size_t outb = (size_t)b * COUT * HWP + (size_t)h * WW + w0;
#pragma unroll
    for (int of = 0; of < 2; ++of) {
        f32x4 aP = of ? acc10 : acc00;
        f32x4 aQ = of ? acc11 : acc01;
        int ocb = wid * 32 + of * 16 + lk * 4;
#pragma unroll
        for (int r = 0; r < 4; ++r) {
            int oc = ocb + r;
            float bi = bias[oc];
            out[outb + (size_t)oc * HWP + pA] = aP[r] + bi;
            out[outb + (size_t)oc * HWP + pB] = aQ[r] + bi;
        }
    }
}

// ================= v1 fallback (R8 kernel, validated; used if ws too small) ====
__global__ __launch_bounds__(256) void k_fused_v1(const float* __restrict__ x,
                                                  const unsigned short* __restrict__ wbf,
                                                  const unsigned short* __restrict__ owbf,
                                                  const float* __restrict__ ob,
                                                  const float* __restrict__ bias,
                                                  float* __restrict__ out) {
    __shared__ __align__(16) char smem[16768];
    char*  ctx    = smem;
    char*  mbase  = smem;
    float* meta_s = (float*)(smem + 13312);

    int blk = blockIdx.x;
    int b   = blk >> 9;
    int rem = blk & 511;
    int h   = rem >> 2;
    int w0  = (rem & 3) << 5;
    int t   = threadIdx.x;

    int p1 = t & 31;
    int cg = t >> 5;
    int l  = t & 63;
    int wid = t >> 6;
    int lm = l & 15, lk = l >> 4;

    const float* xb = x + (size_t)b * CIN * HWP;

#pragma unroll
    for (int c = 0; c < 4; ++c) {
        int j = c * 256 + t;
        if (j < 816) {
            int g   = j / 34;
            int px  = j - g * 34;
            int row = g >> 3;
            int cgj = g & 7;
            int yy = h - 1 + row;
            int xx = w0 - 1 + px;
            bool vld = (yy >= 0) && (yy < HH) && (xx >= 0) && (xx < WW);
            int  sidx = vld ? (yy * WW + xx) : 0;
            float s[8];
#pragma unroll
            for (int i = 0; i < 8; ++i)
                s[i] = vld ? xb[(size_t)(cgj * 8 + i) * HWP + sidx] : 0.f;
            uint4 pk;
            pk.x = (unsigned)f2bf(s[0]) | ((unsigned)f2bf(s[1]) << 16);
            pk.y = (unsigned)f2bf(s[2]) | ((unsigned)f2bf(s[3]) << 16);
            pk.z = (unsigned)f2bf(s[4]) | ((unsigned)f2bf(s[5]) << 16);
            pk.w = (unsigned)f2bf(s[6]) | ((unsigned)f2bf(s[7]) << 16);
            *(uint4*)(ctx + (row * 34 + px) * 128 + ((cgj ^ (px & 7)) << 4)) = pk;
        }
    }
    __syncthreads();

    int ocf = wid >> 1, pxf = wid & 1;
    int spx = pxf * 16 + lm;
    f32x4 sacc = {0.f, 0.f, 0.f, 0.f};
    const unsigned short* sab = owbf + (size_t)(ocf * 16 + lm) * 576 + lk * 8;

#pragma unroll
    for (int tap = 0; tap < 9; ++tap) {
        int ky = tap / 3, kx = tap % 3;
        int cpx = kx + spx;
        int crb = (ky * 34 + cpx) * 128;
        int csw = cpx & 7;
#pragma unroll
        for (int ch = 0; ch < 2; ++ch) {
            short8 a  = *(const short8*)(sab + tap * 64 + ch * 32);
            int kb = ch * 4 + lk;
            short8 bf = *(const short8*)(ctx + crb + (((unsigned)(kb ^ csw)) << 4));
            sacc = __builtin_amdgcn_mfma_f32_16x16x32_bf16(a, bf, sacc, 0, 0, 0);
        }
    }
#pragma unroll
    for (int r = 0; r < 4; ++r) {
        int oc = ocf * 16 + lk * 4 + r;
        if (oc < 27) {
            float v = sacc[r] + ob[oc];
            if (oc < 18) {
                meta_s[(oc & 1) * 288 + (oc >> 1) * 32 + spx] = v;
            } else {
                meta_s[2 * 288 + (oc - 18) * 32 + spx] = 1.f / (1.f + expf(-v));
            }
        }
    }
    __syncthreads();

    f32x4 acc00 = {0.f,0.f,0.f,0.f};
    f32x4 acc01 = {0.f,0.f,0.f,0.f};
    f32x4 acc10 = {0.f,0.f,0.f,0.f};
    f32x4 acc11 = {0.f,0.f,0.f,0.f};

    const unsigned short* arow0 = wbf + (size_t)(wid * 32 + lm) * 576 + lk * 8;
    const unsigned short* arow1 = arow0 + 16 * 576;

    int pA = lm, pB = lm + 16;
    int rbA = pA * 128, rbB = pB * 128;
    int swA = pA & 7,   swB = pB & 7;

    float  cw00, cw01, cw10, cw11;
    float  cc00[8], cc01[8], cc10[8], cc11[8];
    short8 na0[2], na1[2];

#define PREF_CORNERS(KK) do {                                                  \
      int ky = (KK) / 3, kx = (KK) % 3;                                        \
      float offy = meta_s[(KK) * 32 + p1];                                     \
      float offx = meta_s[288 + (KK) * 32 + p1];                               \
      float msk  = meta_s[576 + (KK) * 32 + p1];                               \
      float py = (float)(h - 1 + ky) + offy;                                   \
      float px = (float)(w0 + p1 - 1 + kx) + offx;                             \
      float y0f = floorf(py), x0f = floorf(px);                                \
      float ly = py - y0f, lx = px - x0f;                                      \
      int y0 = (int)y0f, x0i = (int)x0f;                                       \
      int y1 = y0 + 1, x1 = x0i + 1;                                           \
      bool vy0 = (y0 >= 0) && (y0 < HH);                                       \
      bool vy1 = (y1 >= 0) && (y1 < HH);                                       \
      bool vx0 = (x0i >= 0) && (x0i < WW);                                     \
      bool vx1 = (x1 >= 0) && (x1 < WW);                                       \
      int yc0 = min(max(y0, 0), HH - 1), yc1 = min(max(y1, 0), HH - 1);        \
      int xc0 = min(max(x0i, 0), WW - 1), xc1 = min(max(x1, 0), WW - 1);       \
      cw00 = (1.f - ly) * (1.f - lx) * ((vy0 && vx0) ? msk : 0.f);             \
      cw01 = (1.f - ly) * lx         * ((vy0 && vx1) ? msk : 0.f);             \
      cw10 = ly * (1.f - lx)         * ((vy1 && vx0) ? msk : 0.f);             \
      cw11 = ly * lx                 * ((vy1 && vx1) ? msk : 0.f);             \
      int idx00 = yc0 * WW + xc0, idx01 = yc0 * WW + xc1;                      \
      int idx10 = yc1 * WW + xc0, idx11 = yc1 * WW + xc1;                      \
      const float* basec = xb + (size_t)(cg * 8) * HWP;                        \
      _Pragma("unroll")                                                        \
      for (int i = 0; i < 8; ++i) {                                            \
        const float* bc = basec + (size_t)i * HWP;                             \
        cc00[i] = bc[idx00]; cc01[i] = bc[idx01];                              \
        cc10[i] = bc[idx10]; cc11[i] = bc[idx11];                              \
      }                                                                        \
    } while (0)

#define PREF_AFRAG(KK) do {                                                    \
      na0[0] = *(const short8*)(arow0 + (KK) * 64);                            \
      na0[1] = *(const short8*)(arow0 + (KK) * 64 + 32);                       \
      na1[0] = *(const short8*)(arow1 + (KK) * 64);                            \
      na1[1] = *(const short8*)(arow1 + (KK) * 64 + 32);                       \
    } while (0)

    PREF_CORNERS(0);
    PREF_AFRAG(0);

#pragma unroll
    for (int kk = 0; kk < 9; ++kk) {
        {
            char* wdst = mbase + (kk & 1) * 4096;
            float s[8];
#pragma unroll
            for (int i = 0; i < 8; ++i)
                s[i] = cw00 * cc00[i] + cw01 * cc01[i]
                     + cw10 * cc10[i] + cw11 * cc11[i];
            uint4 pk;
            pk.x = (unsigned)f2bf(s[0]) | ((unsigned)f2bf(s[1]) << 16);
            pk.y = (unsigned)f2bf(s[2]) | ((unsigned)f2bf(s[3]) << 16);
            pk.z = (unsigned)f2bf(s[4]) | ((unsigned)f2bf(s[5]) << 16);
            pk.w = (unsigned)f2bf(s[6]) | ((unsigned)f2bf(s[7]) << 16);
            *(uint4*)(wdst + p1 * 128 + (((unsigned)(cg ^ (p1 & 7))) << 4)) = pk;
        }
        if (kk < 8) PREF_CORNERS(kk + 1);
        asm volatile("s_waitcnt lgkmcnt(0)" ::: "memory");
        __builtin_amdgcn_s_barrier();
        __builtin_amdgcn_sched_barrier(0);
        const char* rb = mbase + (kk & 1) * 4096;
#pragma unroll
        for (int sstep = 0; sstep < 2; ++sstep) {
            short8 a0 = na0[sstep];
            short8 a1 = na1[sstep];
            int kb = sstep * 4 + lk;
            short8 b0 = *(const short8*)(rb + rbA + ((kb ^ swA) << 4));
            short8 b1 = *(const short8*)(rb + rbB + ((kb ^ swB) << 4));
            acc00 = __builtin_amdgcn_mfma_f32_16x16x32_bf16(a0, b0, acc00, 0, 0, 0);
            acc01 = __builtin_amdgcn_mfma_f32_16x16x32_bf16(a0, b1, acc01, 0, 0, 0);
            acc10 = __builtin_amdgcn_mfma_f32_16x16x32_bf16(a1, b0, acc10, 0, 0, 0);
            acc11 = __builtin_amdgcn_mfma_f32_16x16x32_bf16(a1, b1, acc11, 0, 0, 0);
        }
        if (kk < 8) PREF_AFRAG(kk + 1);
    }
#undef PREF_CORNERS
#undef PREF_AFRAG

    size_t outb = (size_t)b * COUT * HWP + (size_t)h * WW + w0;
#pragma unroll
    for (int of = 0; of < 2; ++of) {
        f32x4 aP = of ? acc10 : acc00;
        f32x4 aQ = of ? acc11 : acc01;
        int ocb = wid * 32 + of * 16 + lk * 4;
#pragma unroll
        for (int r = 0; r < 4; ++r) {
            int oc = ocb + r;
            float bi = bias[oc];
            out[outb + (size_t)oc * HWP + pA] = aP[r] + bi;
            out[outb + (size_t)oc * HWP + pB] = aQ[r] + bi;
        }
    }
}

extern "C" void kernel_launch(void* const* d_in, const int* in_sizes, int n_in,
                              void* d_out, int out_size, void* d_ws, size_t ws_size,
                              hipStream_t stream) {
    const float* x    = (const float*)d_in[0];
    const float* ow   = (const float*)d_in[1];
    const float* ob   = (const float*)d_in[2];
    const float* wgt  = (const float*)d_in[3];
    const float* bias = (const float*)d_in[4];
    float* out = (float*)d_out;
    char* ws = (char*)d_ws;

    unsigned short* wbf  = (unsigned short*)(ws + WBF_B);
    unsigned short* owbf = (unsigned short*)(ws + OWBF_B);
    unsigned short* xt   = (unsigned short*)(ws + XT_B);

    hipLaunchKernelGGL(k_prep_w, dim3(288), dim3(256), 0, stream, wgt, ow, wbf, owbf);
    if (ws_size >= WS_NEED) {
        hipLaunchKernelGGL(k_xt, dim3(2048), dim3(256), 0, stream, x, xt);
        hipLaunchKernelGGL(k_fused_v2, dim3(2048), dim3(256), 0, stream,
                           xt, wbf, owbf, ob, bias, out);
    } else {
        hipLaunchKernelGGL(k_fused_v1, dim3(2048), dim3(256), 0, stream,
                           x, wbf, owbf, ob, bias, out);
    }
}

// Round 15
// 96.308 us; speedup vs baseline: 3.0429x; 1.0039x over previous
//
#include <hip/hip_runtime.h>
#include <math.h>

#define HH   128
#define WW   128
#define HWP  16384      // H*W
#define CIN  64
#define COUT 128

typedef float  f32x4  __attribute__((ext_vector_type(4)));
typedef short  short8 __attribute__((ext_vector_type(8)));

// ws layout (bytes): wbf [128][576] bf16 @0 (147456); owbf [32][576] bf16 @147456
// (73728); xt NHWC bf16 [4*16384][64] @221184 (8388608). NEED = 8609792.
#define WBF_B   ((size_t)0)
#define OWBF_B  ((size_t)147456)
#define XT_B    ((size_t)221184)
#define WS_NEED ((size_t)8609792)

__device__ inline unsigned short f2bf(float f) {
    unsigned u = __builtin_bit_cast(unsigned, f);
    return (unsigned short)((u + 0x7FFFu + ((u >> 16) & 1u)) >> 16);   // RNE
}

// ---------------- prep: bf16 weight transposes ----------------
__global__ __launch_bounds__(256) void k_prep_w(const float* __restrict__ wgt,
                                                const float* __restrict__ ow,
                                                unsigned short* __restrict__ wbf,
                                                unsigned short* __restrict__ owbf) {
    int tid = blockIdx.x * 256 + threadIdx.x;   // 288*256 = 73728 exactly
    {
        int oc = tid / 576;
        int r  = tid - oc * 576;
        int kk = r >> 6;
        int c  = r & 63;
        wbf[tid] = f2bf(wgt[((size_t)oc * CIN + c) * 9 + kk]);
    }
    if (tid < 32 * 576) {
        int oc  = tid / 576;
        int r   = tid - oc * 576;
        int tap = r >> 6;
        int c   = r & 63;
        owbf[tid] = (oc < 27) ? f2bf(ow[((size_t)oc * CIN + c) * 9 + tap]) : 0;
    }
}

// ---------------- prep: x NCHW fp32 -> NHWC bf16 ----------------
__global__ __launch_bounds__(256) void k_xt(const float* __restrict__ x,
                                            unsigned short* __restrict__ xt) {
    int t = threadIdx.x;
    int cgrp = t & 7, px = t >> 3;            // px 0..31
    int pix = blockIdx.x * 32 + px;           // grid 2048
    int b = pix >> 14, hw = pix & 16383;
    const float* xp = x + (size_t)b * CIN * HWP + (size_t)(cgrp * 8) * HWP + hw;
    unsigned pk[4];
#pragma unroll
    for (int d = 0; d < 4; ++d) {
        float lo = xp[(size_t)(2 * d) * HWP];
        float hi = xp[(size_t)(2 * d + 1) * HWP];
        pk[d] = (unsigned)f2bf(lo) | ((unsigned)f2bf(hi) << 16);
    }
    *(uint4*)(xt + (size_t)pix * 64 + cgrp * 8) = *(uint4*)pk;
}

// ================= v2: NHWC-bf16 fused kernel (R11 structure) =================
// block = 32 pixels of one row x all 128 oc; 256 threads; LDS 11.6 KB
// staging lane map: cg = t&7, px = t>>3 (R11's +18% lever).
// R15: SINGLE-SLOT corner pipeline. Loop order combine(kk) -> issue loads(kk+1)
// into the SAME cc/cw regs -> barrier -> MFMA(kk). Same overlap window (loads
// in flight across barrier+MFMA+addr-calc), half the pipeline registers
// (cc 32->16, cw 8->4) -- aiming for natural VGPR<=64 so waves/CU doubles
// (m69 tier at 64). R10 lesson: never force via __launch_bounds__ min-waves.
__global__ __launch_bounds__(256) void k_fused_v2(const unsigned short* __restrict__ xt,
                                                  const unsigned short* __restrict__ wbf,
                                                  const unsigned short* __restrict__ owbf,
                                                  const float* __restrict__ ob,
                                                  const float* __restrict__ bias,
                                                  float* __restrict__ out) {
    __shared__ __align__(16) char smem[11648];
    char*  mbase  = smem;                    // 2 x 4KB bf16 [32p][64k] swizzled dbuf
    float* meta_s = (float*)(smem + 8192);   // [comp][kk][p] 3456B

    int blk = blockIdx.x;                 // 2048
    int b   = blk >> 9;
    int rem = blk & 511;
    int h   = rem >> 2;
    int w0  = (rem & 3) << 5;
    int t   = threadIdx.x;

    int p1 = t >> 3;                      // pixel in tile (staging role)
    int cg = t & 7;                       // 8-channel group (staging role)
    int l  = t & 63;
    int wid = t >> 6;                     // wave id
    int lm = l & 15, lk = l >> 4;

    const unsigned short* xbt = xt + (size_t)b * HWP * 64;

    // ===== stage A: offset conv, B-frags DIRECT from global xt (no LDS) =====
    int ocf = wid >> 1, pxf = wid & 1;    // wave quadrant: oc[ocf*16+), px[pxf*16+)
    int spx = pxf * 16 + lm;
    f32x4 sacc = {0.f, 0.f, 0.f, 0.f};
    const unsigned short* sab = owbf + (size_t)(ocf * 16 + lm) * 576 + lk * 8;

#pragma unroll
    for (int tap = 0; tap < 9; ++tap) {
        int ky = tap / 3, kx = tap % 3;
        int yy = h - 1 + ky;
        int xx = w0 - 1 + kx + spx;
        bool vld = (yy >= 0) && (yy < HH) && (xx >= 0) && (xx < WW);
        int yc = min(max(yy, 0), HH - 1), xc = min(max(xx, 0), WW - 1);
        const unsigned short* bp = xbt + (size_t)(yc * WW + xc) * 64 + lk * 8;
#pragma unroll
        for (int ch = 0; ch < 2; ++ch) {
            short8 a = *(const short8*)(sab + tap * 64 + ch * 32);
            uint4 v = *(const uint4*)(bp + ch * 32);
            v.x = vld ? v.x : 0u;  v.y = vld ? v.y : 0u;
            v.z = vld ? v.z : 0u;  v.w = vld ? v.w : 0u;
            sacc = __builtin_amdgcn_mfma_f32_16x16x32_bf16(a, __builtin_bit_cast(short8, v), sacc, 0, 0, 0);
        }
    }
    // postprocess own quadrant -> meta_s (C map: col=lane&15 -> px, row=lk*4+r -> oc)
#pragma unroll
    for (int r = 0; r < 4; ++r) {
        int oc = ocf * 16 + lk * 4 + r;
        if (oc < 27) {
            float v = sacc[r] + ob[oc];
            if (oc < 18) {
                meta_s[(oc & 1) * 288 + (oc >> 1) * 32 + spx] = v;
            } else {
                meta_s[2 * 288 + (oc - 18) * 32 + spx] = 1.f / (1.f + expf(-v));
            }
        }
    }
    __syncthreads();   // meta_s ready

    // ================= main: pipelined bilinear (bf16x8 corners) -> MFMA =======
    f32x4 acc00 = {0.f,0.f,0.f,0.f};
    f32x4 acc01 = {0.f,0.f,0.f,0.f};
    f32x4 acc10 = {0.f,0.f,0.f,0.f};
    f32x4 acc11 = {0.f,0.f,0.f,0.f};

    const unsigned short* arow0 = wbf + (size_t)(wid * 32 + lm) * 576 + lk * 8;
    const unsigned short* arow1 = arow0 + 16 * 576;

    int pA = lm, pB = lm + 16;
    int rbA = pA * 128, rbB = pB * 128;
    int swA = pA & 7,   swB = pB & 7;

    // SINGLE-SLOT pipeline registers (R15: was [2] -> halves live regs)
    uint4 cc00, cc01, cc10, cc11;
    float cw00, cw01, cw10, cw11;

    const unsigned short* xbc = xbt + cg * 8;   // this thread's channel slice

#define PREF_CORNERS(KK) do {                                                  \
      int ky_ = (KK) / 3, kx_ = (KK) % 3;                                      \
      float offy = meta_s[(KK) * 32 + p1];                                     \
      float offx = meta_s[288 + (KK) * 32 + p1];                               \
      float msk  = meta_s[576 + (KK) * 32 + p1];                               \
      float py = (float)(h - 1 + ky_) + offy;                                  \
      float px = (float)(w0 + p1 - 1 + kx_) + offx;                            \
      float y0f = floorf(py), x0f = floorf(px);                                \
      float ly = py - y0f, lx = px - x0f;                                      \
      int y0 = (int)y0f, x0i = (int)x0f;                                       \
      int y1 = y0 + 1, x1 = x0i + 1;                                           \
      bool vy0 = (y0 >= 0) && (y0 < HH);                                       \
      bool vy1 = (y1 >= 0) && (y1 < HH);                                       \
      bool vx0 = (x0i >= 0) && (x0i < WW);                                     \
      bool vx1 = (x1 >= 0) && (x1 < WW);                                       \
      int yc0 = min(max(y0, 0), HH - 1), yc1 = min(max(y1, 0), HH - 1);        \
      int xc0 = min(max(x0i, 0), WW - 1), xc1 = min(max(x1, 0), WW - 1);       \
      cw00 = (1.f - ly) * (1.f - lx) * ((vy0 && vx0) ? msk : 0.f);             \
      cw01 = (1.f - ly) * lx         * ((vy0 && vx1) ? msk : 0.f);             \
      cw10 = ly * (1.f - lx)         * ((vy1 && vx0) ? msk : 0.f);             \
      cw11 = ly * lx                 * ((vy1 && vx1) ? msk : 0.f);             \
      cc00 = *(const uint4*)(xbc + (size_t)(yc0 * WW + xc0) * 64);             \
      cc01 = *(const uint4*)(xbc + (size_t)(yc0 * WW + xc1) * 64);             \
      cc10 = *(const uint4*)(xbc + (size_t)(yc1 * WW + xc0) * 64);             \
      cc11 = *(const uint4*)(xbc + (size_t)(yc1 * WW + xc1) * 64);             \
    } while (0)

    PREF_CORNERS(0);

#pragma unroll
    for (int kk = 0; kk < 9; ++kk) {
        const int cur = kk & 1;
        // ---- combine (waits this tile's corners) + pack + swizzled LDS write --
        {
            char* wdst = mbase + cur * 4096;
            unsigned pk[4];
#pragma unroll
            for (int d = 0; d < 4; ++d) {
                unsigned u0 = (&cc00.x)[d], u1 = (&cc01.x)[d];
                unsigned u2 = (&cc10.x)[d], u3 = (&cc11.x)[d];
                float lo = cw00 * __builtin_bit_cast(float, u0 << 16)
                         + cw01 * __builtin_bit_cast(float, u1 << 16)
                         + cw10 * __builtin_bit_cast(float, u2 << 16)
                         + cw11 * __builtin_bit_cast(float, u3 << 16);
                float hi = cw00 * __builtin_bit_cast(float, u0 & 0xFFFF0000u)
                         + cw01 * __builtin_bit_cast(float, u1 & 0xFFFF0000u)
                         + cw10 * __builtin_bit_cast(float, u2 & 0xFFFF0000u)
                         + cw11 * __builtin_bit_cast(float, u3 & 0xFFFF0000u);
                pk[d] = (unsigned)f2bf(lo) | ((unsigned)f2bf(hi) << 16);
            }
            *(uint4*)(wdst + p1 * 128 + (((unsigned)(cg ^ (p1 & 7))) << 4)) = *(uint4*)pk;
        }

        // ---- issue NEXT tile's corner loads into the SAME regs (WAR-safe) ----
        if (kk < 8) PREF_CORNERS(kk + 1);

        // ---- raw barrier: order LDS, leave global prefetches in flight ----
        asm volatile("s_waitcnt lgkmcnt(0)" ::: "memory");
        __builtin_amdgcn_s_barrier();
        __builtin_amdgcn_sched_barrier(0);

        // ---- MFMA (tile kk); A-frags loaded inline (L2-resident wbf) ----
        const char* rb = mbase + cur * 4096;
#pragma unroll
        for (int sstep = 0; sstep < 2; ++sstep) {
            short8 a0 = *(const short8*)(arow0 + kk * 64 + sstep * 32);
            short8 a1 = *(const short8*)(arow1 + kk * 64 + sstep * 32);
            int kb = sstep * 4 + lk;
            short8 b0 = *(const short8*)(rb + rbA + ((kb ^ swA) << 4));
            short8 b1 = *(const short8*)(rb + rbB + ((kb ^ swB) << 4));
            acc00 = __builtin_amdgcn_mfma_f32_16x16x32_bf16(a0, b0, acc00, 0, 0, 0);
            acc01 = __builtin_amdgcn_mfma_f32_16x16x32_bf16(a0, b1, acc01, 0, 0, 0);
            acc10 = __builtin_amdgcn_mfma_f32_16x16x32_bf16(a1, b0, acc10, 0, 0, 0);
            acc11 = __builtin_amdgcn_mfma_f32_16x16x32_bf16(a1, b1, acc11, 0, 0, 0);
        }
    }
#undef PREF_CORNERS

    // ---- epilogue: bias + stores ----
    size_t outb = (size_t)b * COUT * HWP + (size_t)h * WW + w0;
#pragma unroll
    for (int of = 0; of < 2; ++of) {
        f32x4 aP = of ? acc10 : acc00;
        f32x4 aQ = of ? acc11 : acc01;
        int ocb = wid * 32 + of * 16 + lk * 4;
#pragma unroll
        for (int r = 0; r < 4; ++r) {
            int oc = ocb + r;
            float bi = bias[oc];
            out[outb + (size_t)oc * HWP + pA] = aP[r] + bi;
            out[outb + (size_t)oc * HWP + pB] = aQ[r] + bi;
        }
    }
}

// ================= v1 fallback (R8 kernel, validated; used if ws too small) ====
__global__ __launch_bounds__(256) void k_fused_v1(const float* __restrict__ x,
                                                  const unsigned short* __restrict__ wbf,
                                                  const unsigned short* __restrict__ owbf,
                                                  const float* __restrict__ ob,
                                                  const float* __restrict__ bias,
                                                  float* __restrict__ out) {
    __shared__ __align__(16) char smem[16768];
    char*  ctx    = smem;
    char*  mbase  = smem;
    float* meta_s = (float*)(smem + 13312);

    int blk = blockIdx.x;
    int b   = blk >> 9;
    int rem = blk & 511;
    int h   = rem >> 2;
    int w0  = (rem & 3) << 5;
    int t   = threadIdx.x;

    int p1 = t & 31;
    int cg = t >> 5;
    int l  = t & 63;
    int wid = t >> 6;
    int lm = l & 15, lk = l >> 4;

    const float* xb = x + (size_t)b * CIN * HWP;

#pragma unroll
    for (int c = 0; c < 4; ++c) {
        int j = c * 256 + t;
        if (j < 816) {
            int g   = j / 34;
            int px  = j - g * 34;
            int row = g >> 3;
            int cgj = g & 7;
            int yy = h - 1 + row;
            int xx = w0 - 1 + px;
            bool vld = (yy >= 0) && (yy < HH) && (xx >= 0) && (xx < WW);
            int  sidx = vld ? (yy * WW + xx) : 0;
            float s[8];
#pragma unroll
            for (int i = 0; i < 8; ++i)
                s[i] = vld ? xb[(size_t)(cgj * 8 + i) * HWP + sidx] : 0.f;
            uint4 pk;
            pk.x = (unsigned)f2bf(s[0]) | ((unsigned)f2bf(s[1]) << 16);
            pk.y = (unsigned)f2bf(s[2]) | ((unsigned)f2bf(s[3]) << 16);
            pk.z = (unsigned)f2bf(s[4]) | ((unsigned)f2bf(s[5]) << 16);
            pk.w = (unsigned)f2bf(s[6]) | ((unsigned)f2bf(s[7]) << 16);
            *(uint4*)(ctx + (row * 34 + px) * 128 + ((cgj ^ (px & 7)) << 4)) = pk;
        }
    }
    __syncthreads();

    int ocf = wid >> 1, pxf = wid & 1;
    int spx = pxf * 16 + lm;
    f32x4 sacc = {0.f, 0.f, 0.f, 0.f};
    const unsigned short* sab = owbf + (size_t)(ocf * 16 + lm) * 576 + lk * 8;

#pragma unroll
    for (int tap = 0; tap < 9; ++tap) {
        int ky = tap / 3, kx = tap % 3;
        int cpx = kx + spx;
        int crb = (ky * 34 + cpx) * 128;
        int csw = cpx & 7;
#pragma unroll
        for (int ch = 0; ch < 2; ++ch) {
            short8 a  = *(const short8*)(sab + tap * 64 + ch * 32);
            int kb = ch * 4 + lk;
            short8 bf = *(const short8*)(ctx + crb + (((unsigned)(kb ^ csw)) << 4));
            sacc = __builtin_amdgcn_mfma_f32_16x16x32_bf16(a, bf, sacc, 0, 0, 0);
        }
    }
#pragma unroll
    for (int r = 0; r < 4; ++r) {
        int oc = ocf * 16 + lk * 4 + r;
        if (oc < 27) {
            float v = sacc[r] + ob[oc];
            if (oc < 18) {
                meta_s[(oc & 1) * 288 + (oc >> 1) * 32 + spx] = v;
            } else {
                meta_s[2 * 288 + (oc - 18) * 32 + spx] = 1.f / (1.f + expf(-v));
            }
        }
    }
    __syncthreads();

    f32x4 acc00 = {0.f,0.f,0.f,0.f};
    f32x4 acc01 = {0.f,0.f,0.f,0.f};
    f32x4 acc10 = {0.f,0.f,0.f,0.f};
    f32x4 acc11 = {0.f,0.f,0.f,0.f};

    const unsigned short* arow0 = wbf + (size_t)(wid * 32 + lm) * 576 + lk * 8;
    const unsigned short* arow1 = arow0 + 16 * 576;

    int pA = lm, pB = lm + 16;
    int rbA = pA * 128, rbB = pB * 128;
    int swA = pA & 7,   swB = pB & 7;

    float  cw00, cw01, cw10, cw11;
    float  cc00[8], cc01[8], cc10[8], cc11[8];
    short8 na0[2], na1[2];

#define PREF_CORNERS(KK) do {                                                  \
      int ky = (KK) / 3, kx = (KK) % 3;                                        \
      float offy = meta_s[(KK) * 32 + p1];                                     \
      float offx = meta_s[288 + (KK) * 32 + p1];                               \
      float msk  = meta_s[576 + (KK) * 32 + p1];                               \
      float py = (float)(h - 1 + ky) + offy;                                   \
      float px = (float)(w0 + p1 - 1 + kx) + offx;                             \
      float y0f = floorf(py), x0f = floorf(px);                                \
      float ly = py - y0f, lx = px - x0f;                                      \
      int y0 = (int)y0f, x0i = (int)x0f;                                       \
      int y1 = y0 + 1, x1 = x0i + 1;                                           \
      bool vy0 = (y0 >= 0) && (y0 < HH);                                       \
      bool vy1 = (y1 >= 0) && (y1 < HH);                                       \
      bool vx0 = (x0i >= 0) && (x0i < WW);                                     \
      bool vx1 = (x1 >= 0) && (x1 < WW);                                       \
      int yc0 = min(max(y0, 0), HH - 1), yc1 = min(max(y1, 0), HH - 1);        \
      int xc0 = min(max(x0i, 0), WW - 1), xc1 = min(max(x1, 0), WW - 1);       \
      cw00 = (1.f - ly) * (1.f - lx) * ((vy0 && vx0) ? msk : 0.f);             \
      cw01 = (1.f - ly) * lx         * ((vy0 && vx1) ? msk : 0.f);             \
      cw10 = ly * (1.f - lx)         * ((vy1 && vx0) ? msk : 0.f);             \
      cw11 = ly * lx                 * ((vy1 && vx1) ? msk : 0.f);             \
      int idx00 = yc0 * WW + xc0, idx01 = yc0 * WW + xc1;                      \
      int idx10 = yc1 * WW + xc0, idx11 = yc1 * WW + xc1;                      \
      const float* basec = xb + (size_t)(cg * 8) * HWP;                        \
      _Pragma("unroll")                                                        \
      for (int i = 0; i < 8; ++i) {                                            \
        const float* bc = basec + (size_t)i * HWP;                             \
        cc00[i] = bc[idx00]; cc01[i] = bc[idx01];                              \
        cc10[i] = bc[idx10]; cc11[i] = bc[idx11];                              \
      }                                                                        \
    } while (0)

#define PREF_AFRAG(KK) do {                                                    \
      na0[0] = *(const short8*)(arow0 + (KK) * 64);                            \
      na0[1] = *(const short8*)(arow0 + (KK) * 64 + 32);                       \
      na1[0] = *(const short8*)(arow1 + (KK) * 64);                            \
      na1[1] = *(const short8*)(arow1 + (KK) * 64 + 32);                       \
    } while (0)

    PREF_CORNERS(0);
    PREF_AFRAG(0);

#pragma unroll
    for (int kk = 0; kk < 9; ++kk) {
        {
            char* wdst = mbase + (kk & 1) * 4096;
            float s[8];
#pragma unroll
            for (int i = 0; i < 8; ++i)
                s[i] = cw00 * cc00[i] + cw01 * cc01[i]
                     + cw10 * cc10[i] + cw11 * cc11[i];
            uint4 pk;
            pk.x = (unsigned)f2bf(s[0]) | ((unsigned)f2bf(s[1]) << 16);
            pk.y = (unsigned)f2bf(s[2]) | ((unsigned)f2bf(s[3]) << 16);
            pk.z = (unsigned)f2bf(s[4]) | ((unsigned)f2bf(s[5]) << 16);
            pk.w = (unsigned)f2bf(s[6]) | ((unsigned)f2bf(s[7]) << 16);
            *(uint4*)(wdst + p1 * 128 + (((unsigned)(cg ^ (p1 & 7))) << 4)) = pk;
        }
        if (kk < 8) PREF_CORNERS(kk + 1);
        asm volatile("s_waitcnt lgkmcnt(0)" ::: "memory");
        __builtin_amdgcn_s_barrier();
        __builtin_amdgcn_sched_barrier(0);
        const char* rb = mbase + (kk & 1) * 4096;
#pragma unroll
        for (int sstep = 0; sstep < 2; ++sstep) {
            short8 a0 = na0[sstep];
            short8 a1 = na1[sstep];
            int kb = sstep * 4 + lk;
            short8 b0 = *(const short8*)(rb + rbA + ((kb ^ swA) << 4));
            short8 b1 = *(const short8*)(rb + rbB + ((kb ^ swB) << 4));
            acc00 = __builtin_amdgcn_mfma_f32_16x16x32_bf16(a0, b0, acc00, 0, 0, 0);
            acc01 = __builtin_amdgcn_mfma_f32_16x16x32_bf16(a0, b1, acc01, 0, 0, 0);
            acc10 = __builtin_amdgcn_mfma_f32_16x16x32_bf16(a1, b0, acc10, 0, 0, 0);
            acc11 = __builtin_amdgcn_mfma_f32_16x16x32_bf16(a1, b1, acc11, 0, 0, 0);
        }
        if (kk < 8) PREF_AFRAG(kk + 1);
    }
#undef PREF_CORNERS
#undef PREF_AFRAG

    size_t outb = (size_t)b * COUT * HWP + (size_t)h * WW + w0;
#pragma unroll
    for (int of = 0; of < 2; ++of) {
        f32x4 aP = of ? acc10 : acc00;
        f32x4 aQ = of ? acc11 : acc01;
        int ocb = wid * 32 + of * 16 + lk * 4;
#pragma unroll
        for (int r = 0; r < 4; ++r) {
            int oc = ocb + r;
            float bi = bias[oc];
            out[outb + (size_t)oc * HWP + pA] = aP[r] + bi;
            out[outb + (size_t)oc * HWP + pB] = aQ[r] + bi;
        }
    }
}

extern "C" void kernel_launch(void* const* d_in, const int* in_sizes, int n_in,
                              void* d_out, int out_size, void* d_ws, size_t ws_size,
                              hipStream_t stream) {
    const float* x    = (const float*)d_in[0];
    const float* ow   = (const float*)d_in[1];
    const float* ob   = (const float*)d_in[2];
    const float* wgt  = (const float*)d_in[3];
    const float* bias = (const float*)d_in[4];
    float* out = (float*)d_out;
    char* ws = (char*)d_ws;

    unsigned short* wbf  = (unsigned short*)(ws + WBF_B);
    unsigned short* owbf = (unsigned short*)(ws + OWBF_B);
    unsigned short* xt   = (unsigned short*)(ws + XT_B);

    hipLaunchKernelGGL(k_prep_w, dim3(288), dim3(256), 0, stream, wgt, ow, wbf, owbf);
    if (ws_size >= WS_NEED) {
        hipLaunchKernelGGL(k_xt, dim3(2048), dim3(256), 0, stream, x, xt);
        hipLaunchKernelGGL(k_fused_v2, dim3(2048), dim3(256), 0, stream,
                           xt, wbf, owbf, ob, bias, out);
    } else {
        hipLaunchKernelGGL(k_fused_v1, dim3(2048), dim3(256), 0, stream,
                           x, wbf, owbf, ob, bias, out);
    }
}